// Round 11
// baseline (870.450 us; speedup 1.0000x reference)
//
#include <hip/hip_runtime.h>

#define CIN    32
#define COUT   32
#define KMAX   27
#define SCAN_B 2048

typedef _Float16 h2_t __attribute__((ext_vector_type(2)));

__device__ __forceinline__ float dot2(unsigned f, unsigned w, float a)
{
#if __has_builtin(__builtin_amdgcn_fdot2)
    return __builtin_amdgcn_fdot2(__builtin_bit_cast(h2_t, f),
                                  __builtin_bit_cast(h2_t, w), a, false);
#else
    h2_t ff = __builtin_bit_cast(h2_t, f), ww = __builtin_bit_cast(h2_t, w);
    return a + (float)ff.x * (float)ww.x + (float)ff.y * (float)ww.y;
#endif
}

__device__ __forceinline__ unsigned f2h2(float a, float b)
{
    unsigned short ua = __builtin_bit_cast(unsigned short, (_Float16)a);
    unsigned short ub = __builtin_bit_cast(unsigned short, (_Float16)b);
    return (unsigned)ua | ((unsigned)ub << 16);
}

// ---- prep: pack weights (wH[(k*16+j)*32+o] = pair(W[k][2j][o],W[k][2j+1][o]))
//      and features (fH[g*16+c] = pair(feat[g][2c],feat[g][2c+1])) ----
__global__ void k_prep(const float* __restrict__ w, const float* __restrict__ f,
                       unsigned* __restrict__ wH, unsigned* __restrict__ fH,
                       int wtot, int ftot4)
{
    int t = blockIdx.x * blockDim.x + threadIdx.x;
    int stride = gridDim.x * blockDim.x;
    for (int i = t; i < wtot; i += stride) {
        int o = i & 31, j = (i >> 5) & 15, k = i >> 9;
        wH[i] = f2h2(w[(k * CIN + 2 * j) * COUT + o],
                     w[(k * CIN + 2 * j + 1) * COUT + o]);
    }
    for (int i = t; i < ftot4; i += stride) {
        float4 v = ((const float4*)f)[i];
        uint2 r; r.x = f2h2(v.x, v.y); r.y = f2h2(v.z, v.w);
        ((uint2*)fH)[i] = r;
    }
}

// ---- per-row k-mask (injective within k => 1 bit per (row,k)) ----
__global__ void kb_mask(const int* __restrict__ scatter, unsigned* __restrict__ mask,
                        int npair, int M, int vec_ok)
{
    int k = blockIdx.y;
    const int* sp = scatter + (size_t)k * npair;
    int t = blockIdx.x * blockDim.x + threadIdx.x;
    if (vec_ok) {
        int base = t * 4;
        if (base >= npair) return;
        unsigned kb = 1u << k;
        int4 s4 = *(const int4*)(sp + base);
        if (s4.x < M) atomicOr(&mask[s4.x], kb);
        if (s4.y < M) atomicOr(&mask[s4.y], kb);
        if (s4.z < M) atomicOr(&mask[s4.z], kb);
        if (s4.w < M) atomicOr(&mask[s4.w], kb);
    } else {
        if (t >= npair) return;
        int s = sp[t];
        if (s < M) atomicOr(&mask[s], 1u << k);
    }
}

// ---- scan level 1 ----
__global__ void kb_scan1(const unsigned* __restrict__ mask, int* __restrict__ part, int n)
{
    __shared__ int red[256];
    int base = blockIdx.x * SCAN_B;
    int sum = 0;
    for (int i = threadIdx.x; i < SCAN_B; i += 256) {
        int idx = base + i;
        sum += (idx < n) ? __popc(mask[idx]) : 0;
    }
    red[threadIdx.x] = sum;
    __syncthreads();
    for (int s = 128; s > 0; s >>= 1) {
        if (threadIdx.x < s) red[threadIdx.x] += red[threadIdx.x + s];
        __syncthreads();
    }
    if (threadIdx.x == 0) part[blockIdx.x] = red[0];
}

// ---- scan level 2 ----
__global__ void kb_scan2(int* __restrict__ part, int nb, int* __restrict__ total_out)
{
    __shared__ int a[2048], b[2048];
    int t = threadIdx.x;
    for (int i = t; i < 2048; i += 1024) a[i] = (i < nb) ? part[i] : 0;
    __syncthreads();
    int* src = a; int* dst = b;
    for (int ofs = 1; ofs < 2048; ofs <<= 1) {
        for (int i = t; i < 2048; i += 1024)
            dst[i] = (i >= ofs) ? src[i] + src[i - ofs] : src[i];
        __syncthreads();
        int* tmp = src; src = dst; dst = tmp;
    }
    for (int i = t; i < 2048; i += 1024)
        if (i < nb) part[i] = (i == 0) ? 0 : src[i - 1];
    if (t == 0) *total_out = src[nb - 1];
}

// ---- scan level 3 ----
__global__ void kb_scan3(const unsigned* __restrict__ mask, const int* __restrict__ part,
                         int* __restrict__ row_start, int n)
{
    __shared__ int ts[256];
    int base = blockIdx.x * SCAN_B;
    int v[8];
    int sum = 0;
#pragma unroll
    for (int j = 0; j < 8; ++j) {
        int idx = base + threadIdx.x * 8 + j;
        v[j] = (idx < n) ? __popc(mask[idx]) : 0;
        sum += v[j];
    }
    ts[threadIdx.x] = sum;
    __syncthreads();
    for (int ofs = 1; ofs < 256; ofs <<= 1) {
        int add = (threadIdx.x >= ofs) ? ts[threadIdx.x - ofs] : 0;
        __syncthreads();
        ts[threadIdx.x] += add;
        __syncthreads();
    }
    int excl = (threadIdx.x == 0) ? 0 : ts[threadIdx.x - 1];
    excl += part[blockIdx.x];
#pragma unroll
    for (int j = 0; j < 8; ++j) {
        int idx = base + threadIdx.x * 8 + j;
        if (idx < n) row_start[idx] = excl;
        excl += v[j];
    }
}

// ---- PHASE A: per pair, compute 32-ch partial and store at CSR slot.
//      Half-wave per pair; lane = cout; W[k] column in 16 regs (f16 pairs).
//      Plain 128B store, slot unique per (row,k) -> deterministic, no atomics. ----
__global__ __launch_bounds__(256, 8)
void k_partial(const unsigned* __restrict__ fH, const unsigned* __restrict__ wH,
               const int* __restrict__ gather, const int* __restrict__ scatter,
               const unsigned* __restrict__ mask, const int* __restrict__ row_start,
               float* __restrict__ partials, int npair, int M)
{
    const int k   = blockIdx.y;
    const int o   = threadIdx.x & 31;
    const int sub = threadIdx.x >> 5;
    const int hwb = blockDim.x >> 5;

    unsigned wr[16];
    const unsigned* wb = wH + (k * 16) * 32 + o;
#pragma unroll
    for (int j = 0; j < 16; ++j) wr[j] = wb[j * 32];

    const int* sp = scatter + (size_t)k * npair;
    const int* gp = gather  + (size_t)k * npair;
    const unsigned klow = (1u << k) - 1u;

    for (int p = blockIdx.x * hwb + sub; p < npair; p += gridDim.x * hwb) {
        int s = sp[p];
        if (s >= M) continue;                       // half-wave-uniform branch
        int g = gp[p];
        int slot = row_start[s] + __popc(mask[s] & klow);
        const uint4* fb = (const uint4*)(fH + g * 16);
        uint4 f0 = fb[0], f1 = fb[1], f2 = fb[2], f3 = fb[3];  // uniform -> broadcast
        float a = 0.f;
        a = dot2(f0.x, wr[0],  a); a = dot2(f0.y, wr[1],  a);
        a = dot2(f0.z, wr[2],  a); a = dot2(f0.w, wr[3],  a);
        a = dot2(f1.x, wr[4],  a); a = dot2(f1.y, wr[5],  a);
        a = dot2(f1.z, wr[6],  a); a = dot2(f1.w, wr[7],  a);
        a = dot2(f2.x, wr[8],  a); a = dot2(f2.y, wr[9],  a);
        a = dot2(f2.z, wr[10], a); a = dot2(f2.w, wr[11], a);
        a = dot2(f3.x, wr[12], a); a = dot2(f3.y, wr[13], a);
        a = dot2(f3.z, wr[14], a); a = dot2(f3.w, wr[15], a);
        partials[(size_t)slot * 32 + o] = a;        // coalesced 128B store
    }
}

// ---- PHASE B: per row, sum contiguous partial range (streaming), write out.
//      Sum in e (= k-ascending) order -> deterministic. Write-once output. ----
__global__ __launch_bounds__(1024)
void k_reduce(const float* __restrict__ partials, const int* __restrict__ row_start,
              float* __restrict__ out, int M)
{
    const int o = threadIdx.x & 31;
    int h  = (blockIdx.x * blockDim.x + threadIdx.x) >> 5;
    int nh = (gridDim.x * blockDim.x) >> 5;
    for (int m = h; m < M; m += nh) {
        int e0 = row_start[m], e1 = row_start[m + 1];
        float acc = 0.f;
        for (int e = e0; e < e1; ++e)
            acc += partials[(size_t)e * 32 + o];    // contiguous 128B reads
        out[(size_t)m * COUT + o] = acc;
    }
}

// =========== fallback path kernels (proven R7: CSR list + LDS-weight main) ===========
__global__ void kb_pack3(const float* __restrict__ w, unsigned* __restrict__ wH, int total)
{
    int idx = blockIdx.x * blockDim.x + threadIdx.x;
    if (idx >= total) return;
    int j4 = idx & 3, o = (idx >> 2) & 31, jq = (idx >> 7) & 1, h = (idx >> 8) & 1, k = idx >> 9;
    int j = jq * 4 + j4;
    int i0 = h * 16 + 2 * j;
    wH[idx] = f2h2(w[(k * CIN + i0) * COUT + o], w[(k * CIN + i0 + 1) * COUT + o]);
}

__global__ void kb_build(const int* __restrict__ gather, const int* __restrict__ scatter,
                         const unsigned* __restrict__ mask, const int* __restrict__ row_start,
                         int* __restrict__ list, int npair, int M, int vec_ok)
{
    int k = blockIdx.y;
    const int* sp = scatter + (size_t)k * npair;
    const int* gp = gather  + (size_t)k * npair;
    unsigned klow = (1u << k) - 1u;
    int t = blockIdx.x * blockDim.x + threadIdx.x;
    if (vec_ok) {
        int base = t * 4;
        if (base >= npair) return;
        int4 s4 = *(const int4*)(sp + base);
        int4 g4 = *(const int4*)(gp + base);
        if (s4.x < M) list[row_start[s4.x] + __popc(mask[s4.x] & klow)] = (k << 18) | g4.x;
        if (s4.y < M) list[row_start[s4.y] + __popc(mask[s4.y] & klow)] = (k << 18) | g4.y;
        if (s4.z < M) list[row_start[s4.z] + __popc(mask[s4.z] & klow)] = (k << 18) | g4.z;
        if (s4.w < M) list[row_start[s4.w] + __popc(mask[s4.w] & klow)] = (k << 18) | g4.w;
    } else {
        if (t >= npair) return;
        int s = sp[t];
        if (s < M) list[row_start[s] + __popc(mask[s] & klow)] = (k << 18) | gp[t];
    }
}

__global__ __launch_bounds__(1024, 8)
void kw_main(const unsigned* __restrict__ fH, const uint4* __restrict__ wH,
             const int* __restrict__ row_start, const int* __restrict__ list,
             float* __restrict__ out, int M, int K)
{
    __shared__ uint4 wL[KMAX * 128];
    for (int i = threadIdx.x; i < K * 128; i += 1024) wL[i] = wH[i];
    __syncthreads();
    const int lane = threadIdx.x & 63;
    const int o    = lane & 31;
    const int h    = lane >> 5;
    int wid = (blockIdx.x * 1024 + threadIdx.x) >> 6;
    int nW  = (gridDim.x * 1024) >> 6;
    for (int m = wid; m < M; m += nW) {
        const int e0 = row_start[m], e1 = row_start[m + 1];
        float acc = 0.f;
        for (int e = e0; e < e1; ++e) {
            const int pk = list[e];
            const int k = pk >> 18, g = pk & 0x3FFFF;
            const uint4* fb = (const uint4*)(fH + g * 16 + h * 8);
            uint4 f0 = fb[0], f1 = fb[1];
            const uint4* wb2 = wL + ((k * 2 + h) * 2) * 32 + o;
            uint4 w0 = wb2[0], w1 = wb2[32];
            float s = 0.f;
            s = dot2(f0.x, w0.x, s); s = dot2(f0.y, w0.y, s);
            s = dot2(f0.z, w0.z, s); s = dot2(f0.w, w0.w, s);
            s = dot2(f1.x, w1.x, s); s = dot2(f1.y, w1.y, s);
            s = dot2(f1.z, w1.z, s); s = dot2(f1.w, w1.w, s);
            s += __shfl_xor(s, 32, 64);
            acc += s;
        }
        if (lane < 32) out[(size_t)m * COUT + o] = acc;
    }
}

__global__ __launch_bounds__(256, 4)
void spconv_scatter(const float* __restrict__ feat, const float* __restrict__ weight,
                    const int* __restrict__ gather, const int* __restrict__ scatter,
                    float* __restrict__ out, int npair, int M)
{
    const int k = blockIdx.y;
    const int lane = threadIdx.x & 31;
    const int sub = threadIdx.x >> 5;
    const int pairs_per_blk = blockDim.x >> 5;
    const float* wk = weight + (size_t)k * (CIN * COUT);
    float w[CIN];
#pragma unroll
    for (int i = 0; i < CIN; ++i) w[i] = wk[i * COUT + lane];
    const int* gk = gather + (size_t)k * npair;
    const int* sk = scatter + (size_t)k * npair;
    for (int p = blockIdx.x * pairs_per_blk + sub; p < npair; p += gridDim.x * pairs_per_blk) {
        int s = sk[p];
        if (s >= M) continue;
        int g = gk[p];
        const float4* fr = (const float4*)(feat + (size_t)g * CIN);
        float a = 0.f;
#pragma unroll
        for (int c = 0; c < 8; ++c) {
            float4 f4 = fr[c];
            a = fmaf(f4.x, w[4*c+0], a); a = fmaf(f4.y, w[4*c+1], a);
            a = fmaf(f4.z, w[4*c+2], a); a = fmaf(f4.w, w[4*c+3], a);
        }
        atomicAdd(&out[(size_t)s * COUT + lane], a);
    }
}

extern "C" void kernel_launch(void* const* d_in, const int* in_sizes, int n_in,
                              void* d_out, int out_size, void* d_ws, size_t ws_size,
                              hipStream_t stream)
{
    const float* feat    = (const float*)d_in[0];
    const float* weight  = (const float*)d_in[1];
    const int*   gather  = (const int*)d_in[2];
    const int*   scatter = (const int*)d_in[3];
    float*       out     = (float*)d_out;

    const int N     = in_sizes[0] / CIN;            // input sites (150000)
    const int K     = in_sizes[1] / (CIN * COUT);   // 27
    const int npair = in_sizes[2] / K;              // 150000
    const int M     = out_size / COUT;              // num_out (~2.13M)
    const int NB    = (M + SCAN_B - 1) / SCAN_B;    // scan blocks (~1041)
    const int vec_ok = ((npair & 3) == 0) ? 1 : 0;

    uintptr_t base = (uintptr_t)d_ws;
    auto align256 = [](uintptr_t p) { return (p + 255) & ~(uintptr_t)255; };

    // common prefix: mask | row_start | part | wH | fH
    uintptr_t p_mask = align256(base);                             // M uints
    uintptr_t p_rs   = align256(p_mask + (size_t)M * 4);           // M+1 ints
    uintptr_t p_part = align256(p_rs + ((size_t)M + 1) * 4);       // 2048 ints
    uintptr_t p_wH   = align256(p_part + 2048 * 4);                // K*512 uints
    uintptr_t p_fH   = align256(p_wH + (size_t)K * 512 * 4);       // N*16 uints
    uintptr_t p_var  = align256(p_fH + (size_t)N * 16 * 4);        // partials OR list

    const size_t total_pairs_max = (size_t)K * npair;
    uintptr_t p_endA = p_var + total_pairs_max * 32 * 4;           // partials f32
    uintptr_t p_endL = p_var + total_pairs_max * 4;                // list (fallback)

    const bool okA = (p_endA - base <= ws_size) && (NB <= 2048) && (K <= KMAX);
    const bool okL = (p_endL - base <= ws_size) && (NB <= 2048) && (K <= KMAX)
                     && (N <= 0x40000);

    if (!okA && !okL) {
        hipMemsetAsync(d_out, 0, (size_t)out_size * sizeof(float), stream);
        dim3 grid(160, K);
        spconv_scatter<<<grid, 256, 0, stream>>>(feat, weight, gather, scatter, out, npair, M);
        return;
    }

    unsigned* mask      = (unsigned*)p_mask;
    int*      row_start = (int*)p_rs;
    int*      part      = (int*)p_part;
    unsigned* wH        = (unsigned*)p_wH;
    unsigned* fH        = (unsigned*)p_fH;

    hipMemsetAsync(mask, 0, (size_t)M * 4, stream);

    const int pthreads = vec_ok ? npair / 4 : npair;
    dim3 gp((pthreads + 255) / 256, K);
    kb_mask<<<gp, 256, 0, stream>>>(scatter, mask, npair, M, vec_ok);

    kb_scan1<<<NB, 256, 0, stream>>>(mask, part, M);
    kb_scan2<<<1, 1024, 0, stream>>>(part, NB, row_start + M);
    kb_scan3<<<NB, 256, 0, stream>>>(mask, part, row_start, M);

    if (okA) {
        float* partials = (float*)p_var;
        // pack wH layout for k_partial: (k*16+j)*32+o
        k_prep<<<1024, 256, 0, stream>>>(weight, feat, wH, fH, K * 512, N * 8);
        dim3 ga(512, K);
        k_partial<<<ga, 256, 0, stream>>>(fH, wH, gather, scatter, mask, row_start,
                                          partials, npair, M);
        k_reduce<<<512, 1024, 0, stream>>>(partials, row_start, out, M);
    } else {
        int* list = (int*)p_var;
        kb_pack3<<<(K * 512 + 255) / 256, 256, 0, stream>>>(weight, wH, K * 512);
        k_prep<<<1024, 256, 0, stream>>>(weight, feat, wH, fH, 0, N * 8);  // fH only
        kb_build<<<gp, 256, 0, stream>>>(gather, scatter, mask, row_start, list,
                                         npair, M, vec_ok);
        kw_main<<<512, 1024, 0, stream>>>(fH, (const uint4*)wH, row_start, list, out, M, K);
    }
}